// Round 1
// baseline (90.674 us; speedup 1.0000x reference)
//
#include <hip/hip_runtime.h>
#include <math.h>

#define BATCH    32
#define NHEADS   32
#define KVHEADS  8
#define GRP      4      // NHEADS / KVHEADS
#define HSZ      128
#define BLKSZ    16
#define BPS      128    // blocks per seq
#define NTHREADS 512
#define NPROC    16     // half-wave processors per WG
#define SCALE    0.08838834764831843f   // 1/sqrt(128)

__device__ __forceinline__ void proc_row(const float4 kv, const float4 vv,
                                         const float4* qf, float* m, float* l,
                                         float4* o) {
    float s[GRP];
#pragma unroll
    for (int g = 0; g < GRP; ++g)
        s[g] = qf[g].x * kv.x + qf[g].y * kv.y + qf[g].z * kv.z + qf[g].w * kv.w;
#pragma unroll
    for (int g = 0; g < GRP; ++g) {
        s[g] += __shfl_xor(s[g], 1);
        s[g] += __shfl_xor(s[g], 2);
        s[g] += __shfl_xor(s[g], 4);
        s[g] += __shfl_xor(s[g], 8);
        s[g] += __shfl_xor(s[g], 16);   // stays within 32-lane half
    }
#pragma unroll
    for (int g = 0; g < GRP; ++g) {
        const float sc = s[g] * SCALE;
        const float mn = fmaxf(m[g], sc);
        const float cf = __expf(m[g] - mn);   // m=-inf first iter -> 0
        const float pp = __expf(sc - mn);
        l[g] = l[g] * cf + pp;
        o[g].x = o[g].x * cf + pp * vv.x;
        o[g].y = o[g].y * cf + pp * vv.y;
        o[g].z = o[g].z * cf + pp * vv.z;
        o[g].w = o[g].w * cf + pp * vv.w;
        m[g] = mn;
    }
}

__global__ __launch_bounds__(NTHREADS) void paged_attn_kernel(
    const float* __restrict__ query,        // [B,H,D]
    const float* __restrict__ k_new,        // [B,KVH,D]
    const float* __restrict__ v_new,        // [B,KVH,D]
    const float* __restrict__ k_cache,      // [NB,BLKSZ,KVH,D]
    const float* __restrict__ v_cache,      // [NB,BLKSZ,KVH,D]
    const int*  __restrict__ block_tables,  // [B,BPS]
    const int*  __restrict__ ctx_lens,      // [B]
    float* __restrict__ out)                // [B,H,D]
{
    const int wg   = blockIdx.x;       // 0..255
    const int b    = wg >> 3;
    const int kvh  = wg & 7;
    const int tid  = threadIdx.x;
    const int sub  = tid & 31;         // lane within half-wave
    const int proc = tid >> 5;         // 0..15
    const int ctx  = ctx_lens[b];      // valid positions: t in [0, ctx]

    __shared__ float q_s[GRP][HSZ];
    __shared__ float kn_s[HSZ];
    __shared__ int   bt_s[BPS];
    __shared__ float m_s[NPROC][GRP];
    __shared__ float l_s[NPROC][GRP];
    __shared__ float o_s[NPROC][GRP][HSZ];   // 32 KB

    // ---- RoPE (pos = ctx+1) for q heads and new k; stage block table ----
    {
        const float p = (float)(ctx + 1);
        if (tid < 320) {
            const int   i    = tid & 63;
            const float invf = exp2f(-((float)i / 64.0f) * 13.287712379549449f); // 10000^(-2i/128)
            float s_, c_;
            sincosf(p * invf, &s_, &c_);
            if (tid < 256) {
                const int g = tid >> 6;
                const float* qp = query + ((size_t)b * NHEADS + kvh * GRP + g) * HSZ;
                const float x1 = qp[i], x2 = qp[i + 64];
                q_s[g][i]      = x1 * c_ - x2 * s_;
                q_s[g][i + 64] = x2 * c_ + x1 * s_;
            } else {
                const float* kp = k_new + ((size_t)b * KVHEADS + kvh) * HSZ;
                const float x1 = kp[i], x2 = kp[i + 64];
                kn_s[i]      = x1 * c_ - x2 * s_;
                kn_s[i + 64] = x2 * c_ + x1 * s_;
            }
        } else if (tid < 448) {
            bt_s[tid - 320] = block_tables[b * BPS + (tid - 320)];
        }
    }
    __syncthreads();

    // ---- main loop: each half-wave processor handles t = proc, proc+16, ... ----
    const int d0 = sub << 2;
    float4 qf[GRP];
#pragma unroll
    for (int g = 0; g < GRP; ++g) qf[g] = *(const float4*)&q_s[g][d0];

    float  m[GRP], l[GRP];
    float4 o[GRP];
#pragma unroll
    for (int g = 0; g < GRP; ++g) {
        m[g] = -INFINITY; l[g] = 0.f;
        o[g] = make_float4(0.f, 0.f, 0.f, 0.f);
    }

    for (int t = proc; t < ctx; t += NPROC) {
        const int    blk  = bt_s[t >> 4];
        const size_t base = (((size_t)blk * BLKSZ + (t & 15)) * KVHEADS + kvh) * HSZ + d0;
        const float4 kv = *(const float4*)(k_cache + base);
        const float4 vv = *(const float4*)(v_cache + base);
        proc_row(kv, vv, qf, m, l, o);
    }
    // newest token (t == ctx): roped k_new from LDS, v_new from global.
    // (equivalent to the reference's cache update + gather; inputs stay unmutated)
    if (proc == (ctx & (NPROC - 1))) {
        const float4 kv = *(const float4*)&kn_s[d0];
        const float4 vv = *(const float4*)(v_new + ((size_t)b * KVHEADS + kvh) * HSZ + d0);
        proc_row(kv, vv, qf, m, l, o);
    }

    // ---- write partials, merge across the 16 processors ----
    if (sub == 0) {
#pragma unroll
        for (int g = 0; g < GRP; ++g) { m_s[proc][g] = m[g]; l_s[proc][g] = l[g]; }
    }
#pragma unroll
    for (int g = 0; g < GRP; ++g) *(float4*)&o_s[proc][g][d0] = o[g];
    __syncthreads();

    {
        const int g = tid >> 7;       // 0..3
        const int d = tid & 127;
        float mt = -INFINITY;
#pragma unroll
        for (int p = 0; p < NPROC; ++p) mt = fmaxf(mt, m_s[p][g]);
        float lt = 0.f, ot = 0.f;
#pragma unroll
        for (int p = 0; p < NPROC; ++p) {
            const float w = __expf(m_s[p][g] - mt);
            lt += l_s[p][g] * w;
            ot += o_s[p][g][d] * w;
        }
        out[((size_t)b * NHEADS + kvh * GRP + g) * HSZ + d] = ot / lt;
    }
}

extern "C" void kernel_launch(void* const* d_in, const int* in_sizes, int n_in,
                              void* d_out, int out_size, void* d_ws, size_t ws_size,
                              hipStream_t stream) {
    const float* query        = (const float*)d_in[0];
    const float* k_new        = (const float*)d_in[1];
    const float* v_new        = (const float*)d_in[2];
    const float* k_cache      = (const float*)d_in[3];
    const float* v_cache      = (const float*)d_in[4];
    const int*   block_tables = (const int*)d_in[5];
    const int*   ctx_lens     = (const int*)d_in[6];
    float*       out          = (float*)d_out;

    paged_attn_kernel<<<dim3(BATCH * KVHEADS), dim3(NTHREADS), 0, stream>>>(
        query, k_new, v_new, k_cache, v_cache, block_tables, ctx_lens, out);
}

// Round 2
// 82.744 us; speedup vs baseline: 1.0958x; 1.0958x over previous
//
#include <hip/hip_runtime.h>
#include <math.h>

#define BATCH    32
#define NHEADS   32
#define KVHEADS  8
#define GRP      4      // NHEADS / KVHEADS
#define HSZ      128
#define BLKSZ    16
#define BPS      128    // blocks per seq
#define NTHREADS 512
#define NPROC    16     // half-wave processors per WG
#define CHUNK    256    // tokens per split
#define NSPLIT   8      // 2048 / CHUNK
#define SCALE    0.08838834764831843f   // 1/sqrt(128)

__device__ __forceinline__ void proc_row(const float4 kv, const float4 vv,
                                         const float4* qf, float* m, float* l,
                                         float4* o) {
    float s[GRP];
#pragma unroll
    for (int g = 0; g < GRP; ++g)
        s[g] = qf[g].x * kv.x + qf[g].y * kv.y + qf[g].z * kv.z + qf[g].w * kv.w;
#pragma unroll
    for (int g = 0; g < GRP; ++g) {
        s[g] += __shfl_xor(s[g], 1);
        s[g] += __shfl_xor(s[g], 2);
        s[g] += __shfl_xor(s[g], 4);
        s[g] += __shfl_xor(s[g], 8);
        s[g] += __shfl_xor(s[g], 16);   // stays within 32-lane half
    }
#pragma unroll
    for (int g = 0; g < GRP; ++g) {
        const float sc = s[g] * SCALE;
        const float mn = fmaxf(m[g], sc);
        const float cf = __expf(m[g] - mn);   // m=-inf first iter -> 0
        const float pp = __expf(sc - mn);
        l[g] = l[g] * cf + pp;
        o[g].x = o[g].x * cf + pp * vv.x;
        o[g].y = o[g].y * cf + pp * vv.y;
        o[g].z = o[g].z * cf + pp * vv.z;
        o[g].w = o[g].w * cf + pp * vv.w;
        m[g] = mn;
    }
}

// ---------------- split kernel: one WG per (b, kvh, chunk) ----------------
__global__ __launch_bounds__(NTHREADS) void pa_partial(
    const float* __restrict__ query,
    const float* __restrict__ k_new,
    const float* __restrict__ v_new,
    const float* __restrict__ k_cache,
    const float* __restrict__ v_cache,
    const int*  __restrict__ block_tables,
    const int*  __restrict__ ctx_lens,
    float* __restrict__ pm, float* __restrict__ pl, float* __restrict__ po)
{
    const int wg    = blockIdx.x;
    const int chunk = wg & (NSPLIT - 1);
    const int kvh   = (wg >> 3) & (KVHEADS - 1);
    const int b     = wg >> 6;
    const int ctx   = ctx_lens[b];
    const int t0    = chunk * CHUNK;
    if (t0 > ctx) return;                 // inactive split: reduce never reads it

    const int tid  = threadIdx.x;
    const int sub  = tid & 31;
    const int proc = tid >> 5;

    __shared__ float q_s[GRP][HSZ];
    __shared__ float kn_s[HSZ];
    __shared__ int   bt_s[CHUNK / BLKSZ];
    __shared__ float m_s[NPROC][GRP];
    __shared__ float l_s[NPROC][GRP];
    __shared__ float o_s[NPROC][GRP][HSZ];

    // ---- RoPE (pos = ctx+1) for q heads and new k; stage block table ----
    {
        const float p = (float)(ctx + 1);
        if (tid < 320) {
            const int   i    = tid & 63;
            const float invf = exp2f(-((float)i / 64.0f) * 13.287712379549449f); // 10000^(-2i/128)
            float s_, c_;
            sincosf(p * invf, &s_, &c_);
            if (tid < 256) {
                const int g = tid >> 6;
                const float* qp = query + ((size_t)b * NHEADS + kvh * GRP + g) * HSZ;
                const float x1 = qp[i], x2 = qp[i + 64];
                q_s[g][i]      = x1 * c_ - x2 * s_;
                q_s[g][i + 64] = x2 * c_ + x1 * s_;
            } else {
                const float* kp = k_new + ((size_t)b * KVHEADS + kvh) * HSZ;
                const float x1 = kp[i], x2 = kp[i + 64];
                kn_s[i]      = x1 * c_ - x2 * s_;
                kn_s[i + 64] = x2 * c_ + x1 * s_;
            }
        } else if (tid < 320 + CHUNK / BLKSZ) {
            bt_s[tid - 320] = block_tables[b * BPS + (t0 >> 4) + (tid - 320)];
        }
    }
    __syncthreads();

    const int d0 = sub << 2;
    float4 qf[GRP];
#pragma unroll
    for (int g = 0; g < GRP; ++g) qf[g] = *(const float4*)&q_s[g][d0];

    float  m[GRP], l[GRP];
    float4 o[GRP];
#pragma unroll
    for (int g = 0; g < GRP; ++g) {
        m[g] = -INFINITY; l[g] = 0.f;
        o[g] = make_float4(0.f, 0.f, 0.f, 0.f);
    }

    // ---- cache rows t in [t0, min(t0+CHUNK, ctx)), unrolled x2 ----
    const int tend = min(t0 + CHUNK, ctx);
    int t = t0 + proc;
    for (; t + NPROC < tend; t += 2 * NPROC) {
        const int    blk0 = bt_s[(t - t0) >> 4];
        const int    blk1 = bt_s[((t - t0) >> 4) + 1];
        const int    off  = t & 15;
        const size_t a0 = (((size_t)blk0 * BLKSZ + off) * KVHEADS + kvh) * HSZ + d0;
        const size_t a1 = (((size_t)blk1 * BLKSZ + off) * KVHEADS + kvh) * HSZ + d0;
        const float4 kv0 = *(const float4*)(k_cache + a0);
        const float4 vv0 = *(const float4*)(v_cache + a0);
        const float4 kv1 = *(const float4*)(k_cache + a1);
        const float4 vv1 = *(const float4*)(v_cache + a1);
        proc_row(kv0, vv0, qf, m, l, o);
        proc_row(kv1, vv1, qf, m, l, o);
    }
    for (; t < tend; t += NPROC) {
        const int    blk  = bt_s[(t - t0) >> 4];
        const size_t a0 = (((size_t)blk * BLKSZ + (t & 15)) * KVHEADS + kvh) * HSZ + d0;
        const float4 kv = *(const float4*)(k_cache + a0);
        const float4 vv = *(const float4*)(v_cache + a0);
        proc_row(kv, vv, qf, m, l, o);
    }
    // newest token t == ctx lives in chunk ctx>>8 (CHUNK=256, 16 | CHUNK)
    if (chunk == (ctx >> 8) && proc == (ctx & (NPROC - 1))) {
        const float4 kv = *(const float4*)&kn_s[d0];
        const float4 vv = *(const float4*)(v_new + ((size_t)b * KVHEADS + kvh) * HSZ + d0);
        proc_row(kv, vv, qf, m, l, o);
    }

    // ---- merge the 16 processors, write partials to workspace ----
    if (sub == 0) {
#pragma unroll
        for (int g = 0; g < GRP; ++g) { m_s[proc][g] = m[g]; l_s[proc][g] = l[g]; }
    }
#pragma unroll
    for (int g = 0; g < GRP; ++g) *(float4*)&o_s[proc][g][d0] = o[g];
    __syncthreads();

    {
        const int g = tid >> 7;
        const int d = tid & 127;
        float mt = -INFINITY;
#pragma unroll
        for (int p = 0; p < NPROC; ++p) mt = fmaxf(mt, m_s[p][g]);
        float lt = 0.f, ot = 0.f;
#pragma unroll
        for (int p = 0; p < NPROC; ++p) {
            const float w = __expf(m_s[p][g] - mt);
            lt += l_s[p][g] * w;
            ot += o_s[p][g][d] * w;
        }
        const size_t idx = (((size_t)(b * KVHEADS + kvh) * GRP + g) * NSPLIT + chunk);
        if (d == 0) { pm[idx] = mt; pl[idx] = lt; }
        po[idx * HSZ + d] = ot;
    }
}

// ---------------- reduce kernel: one WG per (b, kvh) ----------------
__global__ __launch_bounds__(NTHREADS) void pa_reduce(
    const int*  __restrict__ ctx_lens,
    const float* __restrict__ pm, const float* __restrict__ pl,
    const float* __restrict__ po, float* __restrict__ out)
{
    const int b    = blockIdx.x >> 3;
    const int kvh  = blockIdx.x & 7;
    const int ctx  = ctx_lens[b];
    const int nact = (ctx >> 8) + 1;
    const int tid  = threadIdx.x;
    const int g    = tid >> 7;
    const int d    = tid & 127;
    const size_t idx = ((size_t)(b * KVHEADS + kvh) * GRP + g) * NSPLIT;

    float M = -INFINITY;
    for (int p = 0; p < nact; ++p) M = fmaxf(M, pm[idx + p]);
    float L = 0.f, O = 0.f;
    for (int p = 0; p < nact; ++p) {
        const float w = __expf(pm[idx + p] - M);
        L += pl[idx + p] * w;
        O += po[(idx + p) * HSZ + d] * w;
    }
    out[((size_t)b * NHEADS + kvh * GRP + g) * HSZ + d] = O / L;
}

// ---------------- fallback: round-1 single kernel (if ws too small) ----------------
__global__ __launch_bounds__(NTHREADS) void paged_attn_single(
    const float* __restrict__ query, const float* __restrict__ k_new,
    const float* __restrict__ v_new, const float* __restrict__ k_cache,
    const float* __restrict__ v_cache, const int* __restrict__ block_tables,
    const int* __restrict__ ctx_lens, float* __restrict__ out)
{
    const int wg = blockIdx.x, b = wg >> 3, kvh = wg & 7;
    const int tid = threadIdx.x, sub = tid & 31, proc = tid >> 5;
    const int ctx = ctx_lens[b];

    __shared__ float q_s[GRP][HSZ];
    __shared__ float kn_s[HSZ];
    __shared__ int   bt_s[BPS];
    __shared__ float m_s[NPROC][GRP];
    __shared__ float l_s[NPROC][GRP];
    __shared__ float o_s[NPROC][GRP][HSZ];

    {
        const float p = (float)(ctx + 1);
        if (tid < 320) {
            const int   i    = tid & 63;
            const float invf = exp2f(-((float)i / 64.0f) * 13.287712379549449f);
            float s_, c_;
            sincosf(p * invf, &s_, &c_);
            if (tid < 256) {
                const int g = tid >> 6;
                const float* qp = query + ((size_t)b * NHEADS + kvh * GRP + g) * HSZ;
                const float x1 = qp[i], x2 = qp[i + 64];
                q_s[g][i] = x1 * c_ - x2 * s_; q_s[g][i + 64] = x2 * c_ + x1 * s_;
            } else {
                const float* kp = k_new + ((size_t)b * KVHEADS + kvh) * HSZ;
                const float x1 = kp[i], x2 = kp[i + 64];
                kn_s[i] = x1 * c_ - x2 * s_; kn_s[i + 64] = x2 * c_ + x1 * s_;
            }
        } else if (tid < 448) {
            bt_s[tid - 320] = block_tables[b * BPS + (tid - 320)];
        }
    }
    __syncthreads();

    const int d0 = sub << 2;
    float4 qf[GRP];
#pragma unroll
    for (int g = 0; g < GRP; ++g) qf[g] = *(const float4*)&q_s[g][d0];
    float  m[GRP], l[GRP];
    float4 o[GRP];
#pragma unroll
    for (int g = 0; g < GRP; ++g) {
        m[g] = -INFINITY; l[g] = 0.f; o[g] = make_float4(0.f, 0.f, 0.f, 0.f);
    }
    for (int t = proc; t < ctx; t += NPROC) {
        const int    blk  = bt_s[t >> 4];
        const size_t a0 = (((size_t)blk * BLKSZ + (t & 15)) * KVHEADS + kvh) * HSZ + d0;
        proc_row(*(const float4*)(k_cache + a0), *(const float4*)(v_cache + a0), qf, m, l, o);
    }
    if (proc == (ctx & (NPROC - 1))) {
        proc_row(*(const float4*)&kn_s[d0],
                 *(const float4*)(v_new + ((size_t)b * KVHEADS + kvh) * HSZ + d0), qf, m, l, o);
    }
    if (sub == 0) {
#pragma unroll
        for (int g = 0; g < GRP; ++g) { m_s[proc][g] = m[g]; l_s[proc][g] = l[g]; }
    }
#pragma unroll
    for (int g = 0; g < GRP; ++g) *(float4*)&o_s[proc][g][d0] = o[g];
    __syncthreads();
    {
        const int g = tid >> 7, d = tid & 127;
        float mt = -INFINITY;
#pragma unroll
        for (int p = 0; p < NPROC; ++p) mt = fmaxf(mt, m_s[p][g]);
        float lt = 0.f, ot = 0.f;
#pragma unroll
        for (int p = 0; p < NPROC; ++p) {
            const float w = __expf(m_s[p][g] - mt);
            lt += l_s[p][g] * w; ot += o_s[p][g][d] * w;
        }
        out[((size_t)b * NHEADS + kvh * GRP + g) * HSZ + d] = ot / lt;
    }
}

extern "C" void kernel_launch(void* const* d_in, const int* in_sizes, int n_in,
                              void* d_out, int out_size, void* d_ws, size_t ws_size,
                              hipStream_t stream) {
    const float* query        = (const float*)d_in[0];
    const float* k_new        = (const float*)d_in[1];
    const float* v_new        = (const float*)d_in[2];
    const float* k_cache      = (const float*)d_in[3];
    const float* v_cache      = (const float*)d_in[4];
    const int*   block_tables = (const int*)d_in[5];
    const int*   ctx_lens     = (const int*)d_in[6];
    float*       out          = (float*)d_out;

    const size_t NPART = (size_t)BATCH * KVHEADS * GRP * NSPLIT;   // 8192
    const size_t need  = (NPART * 2 + NPART * HSZ) * sizeof(float); // ~4.26 MB

    if (ws_size >= need) {
        float* pm = (float*)d_ws;
        float* pl = pm + NPART;
        float* po = pl + NPART;
        pa_partial<<<dim3(BATCH * KVHEADS * NSPLIT), dim3(NTHREADS), 0, stream>>>(
            query, k_new, v_new, k_cache, v_cache, block_tables, ctx_lens, pm, pl, po);
        pa_reduce<<<dim3(BATCH * KVHEADS), dim3(NTHREADS), 0, stream>>>(
            ctx_lens, pm, pl, po, out);
    } else {
        paged_attn_single<<<dim3(BATCH * KVHEADS), dim3(NTHREADS), 0, stream>>>(
            query, k_new, v_new, k_cache, v_cache, block_tables, ctx_lens, out);
    }
}